// Round 1
// baseline (575.170 us; speedup 1.0000x reference)
//
#include <hip/hip_runtime.h>
#include <math.h>

#define NN 50000
#define NE 800000
#define F 64
#define NCLS 16

// ---------------- norm pipeline ----------------

__global__ void k_init_deg(float* __restrict__ deg) {
    int i = blockIdx.x * 256 + threadIdx.x;
    if (i < NN) deg[i] = 1.0f;   // self-loop weight
}

__global__ void k_edge_deg(const int* __restrict__ col,
                           const float* __restrict__ w,
                           float* __restrict__ deg) {
    int e = blockIdx.x * 256 + threadIdx.x;
    if (e < NE) atomicAdd(&deg[col[e]], w[e]);
}

__global__ void k_dinv(float* __restrict__ deg) {
    int i = blockIdx.x * 256 + threadIdx.x;
    if (i < NN) deg[i] = 1.0f / sqrtf(deg[i]);   // deg >= 1 always
}

__global__ void k_norm(const int* __restrict__ row,
                       const int* __restrict__ col,
                       const float* __restrict__ w,
                       const float* __restrict__ dinv,
                       float* __restrict__ norm) {
    int e = blockIdx.x * 256 + threadIdx.x;
    if (e < NE) norm[e] = dinv[row[e]] * w[e] * dinv[col[e]];
}

__global__ void k_zero(float* __restrict__ p, int n) {
    int i = blockIdx.x * 256 + threadIdx.x;
    if (i < n) p[i] = 0.0f;
}

// ---------------- dense: Y[n,64] = X[n,64] @ W[64,64] ----------------

__global__ __launch_bounds__(256) void k_mm64(const float* __restrict__ X,
                                              const float* __restrict__ W,
                                              float* __restrict__ Y, int n) {
    __shared__ float sW[64 * 64];
    __shared__ float sX[4][64];
    for (int i = threadIdx.x; i < 64 * 64; i += 256) sW[i] = W[i];
    int lr = threadIdx.x >> 6;      // row within block: 0..3
    int c  = threadIdx.x & 63;      // output feature (lane)
    int r  = blockIdx.x * 4 + lr;
    if (r < n) sX[lr][c] = X[(size_t)r * 64 + c];
    __syncthreads();
    if (r >= n) return;
    float acc = 0.f;
#pragma unroll
    for (int k = 0; k < 64; ++k)
        acc += sX[lr][k] * sW[k * 64 + c];   // sX broadcast, sW stride-1 (2/bank = free)
    Y[(size_t)r * 64 + c] = acc;
}

// ---------------- edge aggregation: B[col] += A[row] * norm ----------------

__global__ __launch_bounds__(256) void k_scatter(const float* __restrict__ A,
                                                 const int* __restrict__ row,
                                                 const int* __restrict__ col,
                                                 const float* __restrict__ norm,
                                                 float* __restrict__ B) {
    int e = blockIdx.x * 4 + (threadIdx.x >> 6);
    if (e >= NE) return;
    int f = threadIdx.x & 63;
    int r = row[e];
    int c = col[e];
    float nv = norm[e];
    float v = A[(size_t)r * 64 + f] * nv;
    atomicAdd(&B[(size_t)c * 64 + f], v);
}

// self-loop contribution (dinv[i]^2 * A[i]) + bias + ReLU, in-place on B
__global__ void k_finish(const float* __restrict__ A,
                         const float* __restrict__ dinv,
                         const float* __restrict__ b,
                         float* __restrict__ B) {
    int i = blockIdx.x * 256 + threadIdx.x;
    if (i < NN * F) {
        int r = i >> 6, f = i & 63;
        float d = dinv[r];
        float v = B[i] + A[i] * d * d + b[f];
        B[i] = fmaxf(v, 0.f);
    }
}

// ---------------- head: softmax(H @ Wout + bout) ----------------

__global__ __launch_bounds__(256) void k_out(const float* __restrict__ H,
                                             const float* __restrict__ Wout,
                                             const float* __restrict__ bout,
                                             float* __restrict__ out) {
    __shared__ float sW[64 * NCLS];
    __shared__ float sb[NCLS];
    for (int i = threadIdx.x; i < 64 * NCLS; i += 256) sW[i] = Wout[i];
    if (threadIdx.x < NCLS) sb[threadIdx.x] = bout[threadIdx.x];
    __syncthreads();
    int lr = threadIdx.x >> 4;      // 16 rows per block
    int c  = threadIdx.x & 15;      // class
    int r  = blockIdx.x * 16 + lr;  // N divisible by 16 (50000/16=3125)
    const float* h = H + (size_t)r * 64;
    float acc = sb[c];
#pragma unroll
    for (int k = 0; k < 64; ++k)
        acc += h[k] * sW[k * NCLS + c];
    // softmax across the 16 class-lanes (contiguous within the wave)
    float m = acc;
#pragma unroll
    for (int o = 8; o >= 1; o >>= 1) m = fmaxf(m, __shfl_xor(m, o, 16));
    float ex = expf(acc - m);
    float s = ex;
#pragma unroll
    for (int o = 8; o >= 1; o >>= 1) s += __shfl_xor(s, o, 16);
    out[(size_t)r * NCLS + c] = ex / s;
}

// ---------------- launch ----------------

extern "C" void kernel_launch(void* const* d_in, const int* in_sizes, int n_in,
                              void* d_out, int out_size, void* d_ws, size_t ws_size,
                              hipStream_t stream) {
    const float* x    = (const float*)d_in[0];
    const int*   ei   = (const int*)d_in[1];   // [2, E] row-major: row then col
    const float* ew   = (const float*)d_in[2];
    const float* W1   = (const float*)d_in[3];
    const float* b1   = (const float*)d_in[4];
    const float* W2   = (const float*)d_in[5];
    const float* b2   = (const float*)d_in[6];
    const float* Wout = (const float*)d_in[7];
    const float* bout = (const float*)d_in[8];
    const int* row = ei;
    const int* col = ei + NE;

    float* ws_f = (float*)d_ws;
    float* dinv = ws_f;                       // NN floats (padded to 50048)
    float* norm = ws_f + 50048;               // NE floats
    float* A    = ws_f + 50048 + NE;          // NN*F
    float* B    = A + (size_t)NN * F;         // NN*F   (total ~29 MB)

    const int nfeat = NN * F;

    // norm pipeline
    k_init_deg<<<(NN + 255) / 256, 256, 0, stream>>>(dinv);
    k_edge_deg<<<(NE + 255) / 256, 256, 0, stream>>>(col, ew, dinv);
    k_dinv<<<(NN + 255) / 256, 256, 0, stream>>>(dinv);
    k_norm<<<(NE + 255) / 256, 256, 0, stream>>>(row, col, ew, dinv, norm);

    // layer 1: A = x @ W1 ; B = scatter(A) + selfloop + b1, ReLU
    k_mm64<<<NN / 4, 256, 0, stream>>>(x, W1, A, NN);
    k_zero<<<(nfeat + 255) / 256, 256, 0, stream>>>(B, nfeat);
    k_scatter<<<NE / 4, 256, 0, stream>>>(A, row, col, norm, B);
    k_finish<<<(nfeat + 255) / 256, 256, 0, stream>>>(A, dinv, b1, B);

    // layer 2: A = B @ W2 ; B = scatter(A) + selfloop + b2, ReLU
    k_mm64<<<NN / 4, 256, 0, stream>>>(B, W2, A, NN);
    k_zero<<<(nfeat + 255) / 256, 256, 0, stream>>>(B, nfeat);
    k_scatter<<<NE / 4, 256, 0, stream>>>(A, row, col, norm, B);
    k_finish<<<(nfeat + 255) / 256, 256, 0, stream>>>(A, dinv, b2, B);

    // head
    k_out<<<NN / 16, 256, 0, stream>>>(B, Wout, bout, (float*)d_out);
}

// Round 2
// 382.124 us; speedup vs baseline: 1.5052x; 1.5052x over previous
//
#include <hip/hip_runtime.h>
#include <math.h>

#define NN 50000
#define NE 800000
#define F 64
#define NCLS 16
#define NTILES 98          // ceil(50000/512)

// ---------------- degree / dinv ----------------

__global__ void k_init_deg(float* __restrict__ deg) {
    int i = blockIdx.x * 256 + threadIdx.x;
    if (i < NN) deg[i] = 1.0f;   // self-loop weight
}

__global__ void k_edge_deg(const int* __restrict__ col,
                           const float* __restrict__ w,
                           float* __restrict__ deg) {
    int e = blockIdx.x * 256 + threadIdx.x;
    if (e < NE) atomicAdd(&deg[col[e]], w[e]);
}

__global__ void k_dinv(float* __restrict__ deg) {
    int i = blockIdx.x * 256 + threadIdx.x;
    if (i < NN) deg[i] = 1.0f / sqrtf(deg[i]);   // deg >= 1 always
}

// ---------------- counting sort by col: hist -> scan -> permute ----------------

__global__ void k_zeroi(int* __restrict__ p, int n) {
    int i = blockIdx.x * 256 + threadIdx.x;
    if (i < n) p[i] = 0;
}

__global__ void k_hist(const int* __restrict__ col, int* __restrict__ hist) {
    int e = blockIdx.x * 256 + threadIdx.x;
    if (e < NE) atomicAdd(&hist[col[e]], 1);
}

// inclusive scan of 512-element tiles (Hillis-Steele in LDS)
__global__ __launch_bounds__(512) void k_scan_tile(const int* __restrict__ in,
                                                   int* __restrict__ out,
                                                   int* __restrict__ tilesum, int n) {
    __shared__ int bufa[512], bufb[512];
    int t = threadIdx.x;
    int i = blockIdx.x * 512 + t;
    bufa[t] = (i < n) ? in[i] : 0;
    __syncthreads();
    int* src = bufa; int* dst = bufb;
#pragma unroll
    for (int off = 1; off < 512; off <<= 1) {
        dst[t] = src[t] + ((t >= off) ? src[t - off] : 0);
        __syncthreads();
        int* tmp = src; src = dst; dst = tmp;
    }
    if (i < n) out[i] = src[t];
    if (t == 511) tilesum[blockIdx.x] = src[511];
}

// inclusive scan of the (small) tile sums, single block
__global__ __launch_bounds__(128) void k_scan_sums(int* __restrict__ tilesum, int ntiles) {
    __shared__ int bufa[128], bufb[128];
    int t = threadIdx.x;
    bufa[t] = (t < ntiles) ? tilesum[t] : 0;
    __syncthreads();
    int* src = bufa; int* dst = bufb;
#pragma unroll
    for (int off = 1; off < 128; off <<= 1) {
        dst[t] = src[t] + ((t >= off) ? src[t - off] : 0);
        __syncthreads();
        int* tmp = src; src = dst; dst = tmp;
    }
    if (t < ntiles) tilesum[t] = src[t];
}

// add tile prefixes; also produce exclusive offsets (write cursors) for permute
__global__ void k_scan_fix(int* __restrict__ incl, const int* __restrict__ hist,
                           const int* __restrict__ tilesum, int* __restrict__ woff, int n) {
    int i = blockIdx.x * 256 + threadIdx.x;
    if (i >= n) return;
    int tile = i >> 9;
    int v = incl[i] + ((tile > 0) ? tilesum[tile - 1] : 0);
    incl[i] = v;
    woff[i] = v - hist[i];   // exclusive start
}

// permute edges into col-sorted order; fuse norm computation
__global__ void k_permute(const int* __restrict__ row, const int* __restrict__ col,
                          const float* __restrict__ w, const float* __restrict__ dinv,
                          int* __restrict__ woff,
                          int* __restrict__ srow, float* __restrict__ snorm) {
    int e = blockIdx.x * 256 + threadIdx.x;
    if (e >= NE) return;
    int r = row[e], c = col[e];
    int pos = atomicAdd(&woff[c], 1);
    srow[pos] = r;
    snorm[pos] = dinv[r] * w[e] * dinv[c];
}

// ---------------- dense: Y[n,64] = X[n,64] @ W[64,64] ----------------

__global__ __launch_bounds__(256) void k_mm64(const float* __restrict__ X,
                                              const float* __restrict__ W,
                                              float* __restrict__ Y, int n) {
    __shared__ float sW[64 * 64];
    __shared__ float sX[4][64];
    for (int i = threadIdx.x; i < 64 * 64; i += 256) sW[i] = W[i];
    int lr = threadIdx.x >> 6;
    int c  = threadIdx.x & 63;
    int r  = blockIdx.x * 4 + lr;
    if (r < n) sX[lr][c] = X[(size_t)r * 64 + c];
    __syncthreads();
    if (r >= n) return;
    float acc = 0.f;
#pragma unroll
    for (int k = 0; k < 64; ++k)
        acc += sX[lr][k] * sW[k * 64 + c];
    Y[(size_t)r * 64 + c] = acc;
}

// ---------------- atomic-free aggregation: one wave per destination node ----------------
// B[n] = relu( sum_in_edges A[src]*norm + dinv[n]^2 * A[n] + bias )

__global__ __launch_bounds__(256) void k_aggregate(const float* __restrict__ A,
                                                   const int* __restrict__ incl,
                                                   const int* __restrict__ srow,
                                                   const float* __restrict__ snorm,
                                                   const float* __restrict__ dinv,
                                                   const float* __restrict__ bias,
                                                   float* __restrict__ B) {
    int node = blockIdx.x * 4 + (threadIdx.x >> 6);
    if (node >= NN) return;
    int f = threadIdx.x & 63;
    int beg = (node == 0) ? 0 : incl[node - 1];
    int end = incl[node];
    float acc0 = 0.f, acc1 = 0.f;
    int e = beg;
    for (; e + 2 <= end; e += 2) {          // 2-way unroll for load ILP
        int   s0 = srow[e],     s1 = srow[e + 1];
        float n0 = snorm[e],    n1 = snorm[e + 1];
        float a0 = A[(size_t)s0 * 64 + f];
        float a1 = A[(size_t)s1 * 64 + f];
        acc0 += a0 * n0;
        acc1 += a1 * n1;
    }
    if (e < end) acc0 += A[(size_t)srow[e] * 64 + f] * snorm[e];
    float d = dinv[node];
    float v = acc0 + acc1 + A[(size_t)node * 64 + f] * d * d + bias[f];
    B[(size_t)node * 64 + f] = fmaxf(v, 0.f);
}

// ---------------- head: softmax(H @ Wout + bout) ----------------

__global__ __launch_bounds__(256) void k_out(const float* __restrict__ H,
                                             const float* __restrict__ Wout,
                                             const float* __restrict__ bout,
                                             float* __restrict__ out) {
    __shared__ float sW[64 * NCLS];
    __shared__ float sb[NCLS];
    for (int i = threadIdx.x; i < 64 * NCLS; i += 256) sW[i] = Wout[i];
    if (threadIdx.x < NCLS) sb[threadIdx.x] = bout[threadIdx.x];
    __syncthreads();
    int lr = threadIdx.x >> 4;
    int c  = threadIdx.x & 15;
    int r  = blockIdx.x * 16 + lr;
    const float* h = H + (size_t)r * 64;
    float acc = sb[c];
#pragma unroll
    for (int k = 0; k < 64; ++k)
        acc += h[k] * sW[k * NCLS + c];
    float m = acc;
#pragma unroll
    for (int o = 8; o >= 1; o >>= 1) m = fmaxf(m, __shfl_xor(m, o, 16));
    float ex = expf(acc - m);
    float s = ex;
#pragma unroll
    for (int o = 8; o >= 1; o >>= 1) s += __shfl_xor(s, o, 16);
    out[(size_t)r * NCLS + c] = ex / s;
}

// ---------------- launch ----------------

extern "C" void kernel_launch(void* const* d_in, const int* in_sizes, int n_in,
                              void* d_out, int out_size, void* d_ws, size_t ws_size,
                              hipStream_t stream) {
    const float* x    = (const float*)d_in[0];
    const int*   ei   = (const int*)d_in[1];   // [2, E]: row then col
    const float* ew   = (const float*)d_in[2];
    const float* W1   = (const float*)d_in[3];
    const float* b1   = (const float*)d_in[4];
    const float* W2   = (const float*)d_in[5];
    const float* b2   = (const float*)d_in[6];
    const float* Wout = (const float*)d_in[7];
    const float* bout = (const float*)d_in[8];
    const int* row = ei;
    const int* col = ei + NE;

    // workspace layout (all recomputed every call — ws is re-poisoned)
    float* ws_f  = (float*)d_ws;
    float* dinv  = ws_f;                            // 50048
    int*   hist  = (int*)(ws_f + 50048);            // 50048
    int*   incl  = hist + 50048;                    // 50048
    int*   woff  = incl + 50048;                    // 50048
    int*   tsum  = woff + 50048;                    // 128
    int*   srow  = tsum + 128;                      // NE
    float* snorm = (float*)(srow + NE);             // NE
    float* A     = snorm + NE;                      // NN*F
    float* B     = A + (size_t)NN * F;              // NN*F  (~33 MB total)

    // dinv
    k_init_deg<<<(NN + 255) / 256, 256, 0, stream>>>(dinv);
    k_edge_deg<<<(NE + 255) / 256, 256, 0, stream>>>(col, ew, dinv);
    k_dinv<<<(NN + 255) / 256, 256, 0, stream>>>(dinv);

    // counting sort by destination (built once, used by both layers)
    k_zeroi<<<(NN + 255) / 256, 256, 0, stream>>>(hist, NN);
    k_hist<<<(NE + 255) / 256, 256, 0, stream>>>(col, hist);
    k_scan_tile<<<NTILES, 512, 0, stream>>>(hist, incl, tsum, NN);
    k_scan_sums<<<1, 128, 0, stream>>>(tsum, NTILES);
    k_scan_fix<<<(NN + 255) / 256, 256, 0, stream>>>(incl, hist, tsum, woff, NN);
    k_permute<<<(NE + 255) / 256, 256, 0, stream>>>(row, col, ew, dinv, woff, srow, snorm);

    // layer 1
    k_mm64<<<NN / 4, 256, 0, stream>>>(x, W1, A, NN);
    k_aggregate<<<(NN + 3) / 4, 256, 0, stream>>>(A, incl, srow, snorm, dinv, b1, B);

    // layer 2
    k_mm64<<<NN / 4, 256, 0, stream>>>(B, W2, A, NN);
    k_aggregate<<<(NN + 3) / 4, 256, 0, stream>>>(A, incl, srow, snorm, dinv, b2, B);

    // head
    k_out<<<NN / 16, 256, 0, stream>>>(B, Wout, bout, (float*)d_out);
}

// Round 3
// 298.193 us; speedup vs baseline: 1.9288x; 1.2815x over previous
//
#include <hip/hip_runtime.h>
#include <math.h>

#define NN 50000
#define NE 800000
#define F 64
#define NCLS 16
#define NTILES 98          // ceil(50000/512)

// ---------------- counting sort by col: hist -> scan -> permute ----------------

__global__ void k_zeroi(int* __restrict__ p, int n) {
    int i = blockIdx.x * 256 + threadIdx.x;
    if (i < n) p[i] = 0;
}

__global__ void k_hist(const int* __restrict__ col, int* __restrict__ hist) {
    int e = blockIdx.x * 256 + threadIdx.x;
    if (e < NE) atomicAdd(&hist[col[e]], 1);
}

// inclusive scan of 512-element tiles (Hillis-Steele in LDS)
__global__ __launch_bounds__(512) void k_scan_tile(const int* __restrict__ in,
                                                   int* __restrict__ out,
                                                   int* __restrict__ tilesum, int n) {
    __shared__ int bufa[512], bufb[512];
    int t = threadIdx.x;
    int i = blockIdx.x * 512 + t;
    bufa[t] = (i < n) ? in[i] : 0;
    __syncthreads();
    int* src = bufa; int* dst = bufb;
#pragma unroll
    for (int off = 1; off < 512; off <<= 1) {
        dst[t] = src[t] + ((t >= off) ? src[t - off] : 0);
        __syncthreads();
        int* tmp = src; src = dst; dst = tmp;
    }
    if (i < n) out[i] = src[t];
    if (t == 511) tilesum[blockIdx.x] = src[511];
}

__global__ __launch_bounds__(128) void k_scan_sums(int* __restrict__ tilesum, int ntiles) {
    __shared__ int bufa[128], bufb[128];
    int t = threadIdx.x;
    bufa[t] = (t < ntiles) ? tilesum[t] : 0;
    __syncthreads();
    int* src = bufa; int* dst = bufb;
#pragma unroll
    for (int off = 1; off < 128; off <<= 1) {
        dst[t] = src[t] + ((t >= off) ? src[t - off] : 0);
        __syncthreads();
        int* tmp = src; src = dst; dst = tmp;
    }
    if (t < ntiles) tilesum[t] = src[t];
}

__global__ void k_scan_fix(int* __restrict__ incl, const int* __restrict__ hist,
                           const int* __restrict__ tilesum, int* __restrict__ woff, int n) {
    int i = blockIdx.x * 256 + threadIdx.x;
    if (i >= n) return;
    int tile = i >> 9;
    int v = incl[i] + ((tile > 0) ? tilesum[tile - 1] : 0);
    incl[i] = v;
    woff[i] = v - hist[i];   // exclusive start
}

// permute edges into col-sorted order; payload packed {src, weight} in one 8B store
__global__ void k_permute(const int* __restrict__ row, const int* __restrict__ col,
                          const float* __restrict__ w,
                          int* __restrict__ woff, int2* __restrict__ sedge) {
    int e = blockIdx.x * 256 + threadIdx.x;
    if (e >= NE) return;
    int c = col[e];
    int pos = atomicAdd(&woff[c], 1);
    int2 ed;
    ed.x = row[e];
    ed.y = __float_as_int(w[e]);
    sedge[pos] = ed;
}

// atomic-free degree from sorted segments: dinv[n] = rsqrt(1 + sum_w)
__global__ void k_deg(const int* __restrict__ incl, const int2* __restrict__ sedge,
                      float* __restrict__ dinv) {
    int n = blockIdx.x * 256 + threadIdx.x;
    if (n >= NN) return;
    int beg = (n == 0) ? 0 : incl[n - 1];
    int end = incl[n];
    float s = 1.0f;                       // self-loop
    for (int e = beg; e < end; ++e) s += __int_as_float(sedge[e].y);
    dinv[n] = rsqrtf(s);
}

// overwrite weight with norm = dinv[src] * w * dinv[dst], in-place on sorted edges
__global__ void k_snorm(const int* __restrict__ incl, int2* __restrict__ sedge,
                        const float* __restrict__ dinv) {
    int n = blockIdx.x * 256 + threadIdx.x;
    if (n >= NN) return;
    int beg = (n == 0) ? 0 : incl[n - 1];
    int end = incl[n];
    float dc = dinv[n];
    for (int e = beg; e < end; ++e) {
        int2 ed = sedge[e];
        ed.y = __float_as_int(dinv[ed.x] * __int_as_float(ed.y) * dc);
        sedge[e] = ed;
    }
}

// ---------------- dense: Y[n,64] = X[n,64] @ W[64,64], 16 rows/block ----------------

__global__ __launch_bounds__(256) void k_mm64(const float* __restrict__ X,
                                              const float* __restrict__ W,
                                              float* __restrict__ Y) {
    __shared__ float sW[64 * 64];     // 16 KB
    __shared__ float sX[16][64];      // 4 KB
    int tid = threadIdx.x;
    int c  = tid & 63;
    int wv = tid >> 6;                // wave id 0..3, handles rows wv*4..wv*4+3
    for (int i = tid; i < 64 * 64; i += 256) sW[i] = W[i];
    int r0 = blockIdx.x * 16;         // 50000/16 = 3125 exact
#pragma unroll
    for (int i = tid; i < 16 * 64; i += 256)
        sX[i >> 6][i & 63] = X[(size_t)(r0 + (i >> 6)) * 64 + (i & 63)];
    __syncthreads();
    int rb = wv * 4;
    float a0 = 0.f, a1 = 0.f, a2 = 0.f, a3 = 0.f;
#pragma unroll
    for (int k = 0; k < 64; k += 4) {
        float4 x0 = *(const float4*)&sX[rb + 0][k];
        float4 x1 = *(const float4*)&sX[rb + 1][k];
        float4 x2 = *(const float4*)&sX[rb + 2][k];
        float4 x3 = *(const float4*)&sX[rb + 3][k];
        float wA = sW[(k + 0) * 64 + c];
        float wB = sW[(k + 1) * 64 + c];
        float wC = sW[(k + 2) * 64 + c];
        float wD = sW[(k + 3) * 64 + c];
        a0 += x0.x * wA + x0.y * wB + x0.z * wC + x0.w * wD;
        a1 += x1.x * wA + x1.y * wB + x1.z * wC + x1.w * wD;
        a2 += x2.x * wA + x2.y * wB + x2.z * wC + x2.w * wD;
        a3 += x3.x * wA + x3.y * wB + x3.z * wC + x3.w * wD;
    }
    Y[(size_t)(r0 + rb + 0) * 64 + c] = a0;
    Y[(size_t)(r0 + rb + 1) * 64 + c] = a1;
    Y[(size_t)(r0 + rb + 2) * 64 + c] = a2;
    Y[(size_t)(r0 + rb + 3) * 64 + c] = a3;
}

// ---------------- aggregation: one wave per node, float4 gather, 4 edges in flight ----
// B[n] = relu( sum_in A[src]*norm + dinv[n]^2 * A[n] + bias )

__global__ __launch_bounds__(256) void k_agg(const float* __restrict__ A,
                                             const int* __restrict__ incl,
                                             const int2* __restrict__ sedge,
                                             const float* __restrict__ dinv,
                                             const float* __restrict__ bias,
                                             float* __restrict__ B) {
    int node = blockIdx.x * 4 + (threadIdx.x >> 6);   // 12500 blocks exact
    int lane = threadIdx.x & 63;
    int slot = lane >> 4;          // 0..3 : which edge of the 4 in flight
    int fg   = lane & 15;          // feature group: features fg*4 .. fg*4+3
    int beg = (node == 0) ? 0 : incl[node - 1];
    int end = incl[node];
    int deg = end - beg;
    float ax = 0.f, ay = 0.f, az = 0.f, aw = 0.f;
    for (int base = 0; base < deg; base += 64) {
        int i = base + lane;
        int2 ed = (i < deg) ? sedge[beg + i] : make_int2(0, 0);  // norm=0 pad
        int m = min(64, deg - base);
        int steps = (m + 3) >> 2;
        for (int t = 0; t < steps; ++t) {
            int idx = (t << 2) + slot;
            int   s  = __shfl(ed.x, idx);
            float nm = __int_as_float(__shfl(ed.y, idx));
            const float4 a = *(const float4*)(A + (size_t)s * 64 + (fg << 2));
            ax += a.x * nm; ay += a.y * nm; az += a.z * nm; aw += a.w * nm;
        }
    }
    // reduce across the 4 slots (lanes xor 16, 32)
#pragma unroll
    for (int o = 16; o <= 32; o <<= 1) {
        ax += __shfl_xor(ax, o);
        ay += __shfl_xor(ay, o);
        az += __shfl_xor(az, o);
        aw += __shfl_xor(aw, o);
    }
    if (slot == 0) {
        float d = dinv[node];
        float d2 = d * d;
        const float4 self = *(const float4*)(A + (size_t)node * 64 + (fg << 2));
        const float4 bb   = *(const float4*)(bias + (fg << 2));
        float4 v;
        v.x = fmaxf(ax + self.x * d2 + bb.x, 0.f);
        v.y = fmaxf(ay + self.y * d2 + bb.y, 0.f);
        v.z = fmaxf(az + self.z * d2 + bb.z, 0.f);
        v.w = fmaxf(aw + self.w * d2 + bb.w, 0.f);
        *(float4*)(B + (size_t)node * 64 + (fg << 2)) = v;
    }
}

// ---------------- head: softmax(H @ Wout + bout) ----------------

__global__ __launch_bounds__(256) void k_out(const float* __restrict__ H,
                                             const float* __restrict__ Wout,
                                             const float* __restrict__ bout,
                                             float* __restrict__ out) {
    __shared__ float sW[64 * NCLS];
    __shared__ float sb[NCLS];
    for (int i = threadIdx.x; i < 64 * NCLS; i += 256) sW[i] = Wout[i];
    if (threadIdx.x < NCLS) sb[threadIdx.x] = bout[threadIdx.x];
    __syncthreads();
    int lr = threadIdx.x >> 4;
    int c  = threadIdx.x & 15;
    int r  = blockIdx.x * 16 + lr;
    const float* h = H + (size_t)r * 64;
    float acc = sb[c];
#pragma unroll
    for (int k = 0; k < 64; ++k)
        acc += h[k] * sW[k * NCLS + c];
    float m = acc;
#pragma unroll
    for (int o = 8; o >= 1; o >>= 1) m = fmaxf(m, __shfl_xor(m, o, 16));
    float ex = expf(acc - m);
    float s = ex;
#pragma unroll
    for (int o = 8; o >= 1; o >>= 1) s += __shfl_xor(s, o, 16);
    out[(size_t)r * NCLS + c] = ex / s;
}

// ---------------- launch ----------------

extern "C" void kernel_launch(void* const* d_in, const int* in_sizes, int n_in,
                              void* d_out, int out_size, void* d_ws, size_t ws_size,
                              hipStream_t stream) {
    const float* x    = (const float*)d_in[0];
    const int*   ei   = (const int*)d_in[1];   // [2, E]: row then col
    const float* ew   = (const float*)d_in[2];
    const float* W1   = (const float*)d_in[3];
    const float* b1   = (const float*)d_in[4];
    const float* W2   = (const float*)d_in[5];
    const float* b2   = (const float*)d_in[6];
    const float* Wout = (const float*)d_in[7];
    const float* bout = (const float*)d_in[8];
    const int* row = ei;
    const int* col = ei + NE;

    // workspace layout (recomputed every call; all offsets keep 16B alignment)
    int*   ip    = (int*)d_ws;
    int*   incl  = ip;                          // 50048
    int*   woff  = ip + 50048;                  // 50048
    int*   hist  = ip + 100096;                 // 50048
    int*   tsum  = ip + 150144;                 // 128
    int2*  sedge = (int2*)(ip + 150272);        // NE int2 (8B aligned)
    float* A     = (float*)(ip + 150272 + 2 * NE);   // NN*F (16B aligned)
    float* B     = A + (size_t)NN * F;               // NN*F
    float* dinv  = B + (size_t)NN * F;               // NN

    // counting sort by destination
    k_zeroi<<<(NN + 255) / 256, 256, 0, stream>>>(hist, NN);
    k_hist<<<(NE + 255) / 256, 256, 0, stream>>>(col, hist);
    k_scan_tile<<<NTILES, 512, 0, stream>>>(hist, incl, tsum, NN);
    k_scan_sums<<<1, 128, 0, stream>>>(tsum, NTILES);
    k_scan_fix<<<(NN + 255) / 256, 256, 0, stream>>>(incl, hist, tsum, woff, NN);
    k_permute<<<(NE + 255) / 256, 256, 0, stream>>>(row, col, ew, woff, sedge);

    // degree + norm from sorted segments (no float atomics)
    k_deg<<<(NN + 255) / 256, 256, 0, stream>>>(incl, sedge, dinv);
    k_snorm<<<(NN + 255) / 256, 256, 0, stream>>>(incl, sedge, dinv);

    // layer 1
    k_mm64<<<NN / 16, 256, 0, stream>>>(x, W1, A);
    k_agg<<<NN / 4, 256, 0, stream>>>(A, incl, sedge, dinv, b1, B);

    // layer 2
    k_mm64<<<NN / 16, 256, 0, stream>>>(B, W2, A);
    k_agg<<<NN / 4, 256, 0, stream>>>(A, incl, sedge, dinv, b2, B);

    // head
    k_out<<<NN / 16, 256, 0, stream>>>(B, Wout, bout, (float*)d_out);
}

// Round 4
// 233.682 us; speedup vs baseline: 2.4613x; 1.2761x over previous
//
#include <hip/hip_runtime.h>
#include <math.h>

#define NN 50000
#define NE 800000
#define F 64
#define NCLS 16

#define BKS 7              // log2(nodes per bucket)
#define BKN 128            // nodes per bucket
#define NBK 391            // ceil(50000/128)
#define B1C 4096           // edges per bucket1 block
#define B1B 196            // ceil(NE/B1C)
#define CAP2 3072          // max edges per bucket (avg 2048, sigma~45)

__global__ void k_zeroi(int* __restrict__ p, int n) {
    int i = blockIdx.x * 256 + threadIdx.x;
    if (i < n) p[i] = 0;
}

// ---------------- pass 0: coarse bucket histogram ----------------

__global__ __launch_bounds__(256) void k_bkhist(const int* __restrict__ col,
                                                int* __restrict__ bkcnt) {
    __shared__ int h[NBK];
    for (int i = threadIdx.x; i < NBK; i += 256) h[i] = 0;
    __syncthreads();
    int stride = gridDim.x * 256;
    for (int e = blockIdx.x * 256 + threadIdx.x; e < NE; e += stride)
        atomicAdd(&h[col[e] >> BKS], 1);
    __syncthreads();
    for (int i = threadIdx.x; i < NBK; i += 256) {
        int v = h[i];
        if (v) atomicAdd(&bkcnt[i], v);
    }
}

// ---------------- scan bucket counts -> bases + cursors (1 block) ----------------

__global__ __launch_bounds__(512) void k_scan_bk(const int* __restrict__ bkcnt,
                                                 int* __restrict__ bkbase,
                                                 int* __restrict__ bkcur) {
    __shared__ int sa[512], sb[512];
    int t = threadIdx.x;
    int c = (t < NBK) ? bkcnt[t] : 0;
    sa[t] = c;
    __syncthreads();
    int* src = sa; int* dst = sb;
#pragma unroll
    for (int off = 1; off < 512; off <<= 1) {
        dst[t] = src[t] + ((t >= off) ? src[t - off] : 0);
        __syncthreads();
        int* tq = src; src = dst; dst = tq;
    }
    if (t < NBK) {
        int excl = src[t] - c;
        bkbase[t] = excl;
        bkcur[t]  = excl;
    }
    if (t == NBK) bkbase[t] = NE;
}

// ---------------- pass 1: group edges by bucket (LDS), flush contiguous runs ------
// payload: {(row<<7)|col_local, weight_bits}

__global__ __launch_bounds__(512) void k_bucket1(const int* __restrict__ row,
                                                 const int* __restrict__ col,
                                                 const float* __restrict__ w,
                                                 int* __restrict__ bkcur,
                                                 int2* __restrict__ tmp) {
    __shared__ int hist[512];
    __shared__ int sa[512], sb[512];
    __shared__ int lbase[512];      // exclusive run starts within stage (sentinel at NBK)
    __shared__ int gbase[512];
    __shared__ int lcur[512];
    __shared__ int2 stage[B1C];
    int t = threadIdx.x;
    int e0 = blockIdx.x * B1C;
    int cnt = min(B1C, NE - e0);
    hist[t] = 0;
    __syncthreads();

    int mykey[8]; int myb[8]; int myw[8]; bool myv[8];
#pragma unroll
    for (int k = 0; k < 8; ++k) {
        int i = t + k * 512;
        myv[k] = (i < cnt);
        if (myv[k]) {
            int e = e0 + i;
            int c = col[e];
            myb[k]   = c >> BKS;
            mykey[k] = (row[e] << BKS) | (c & (BKN - 1));
            myw[k]   = __float_as_int(w[e]);
            atomicAdd(&hist[myb[k]], 1);
        }
    }
    __syncthreads();

    sa[t] = hist[t];
    __syncthreads();
    int* src = sa; int* dst = sb;
#pragma unroll
    for (int off = 1; off < 512; off <<= 1) {
        dst[t] = src[t] + ((t >= off) ? src[t - off] : 0);
        __syncthreads();
        int* tq = src; src = dst; dst = tq;
    }
    int lex = src[t] - hist[t];
    lbase[t] = lex;
    lcur[t]  = lex;
    gbase[t] = (t < NBK && hist[t] > 0) ? atomicAdd(&bkcur[t], hist[t]) : 0;
    __syncthreads();

#pragma unroll
    for (int k = 0; k < 8; ++k) {
        if (myv[k]) {
            int pos = atomicAdd(&lcur[myb[k]], 1);
            stage[pos] = make_int2(mykey[k], myw[k]);
        }
    }
    __syncthreads();

    // flush: element i belongs to run r with lbase[r] <= i < lbase[r+1]
    for (int i = t; i < cnt; i += 512) {
        int lo = 0, hi = NBK;
        while (hi - lo > 1) {
            int mid = (lo + hi) >> 1;
            if (lbase[mid] <= i) lo = mid; else hi = mid;
        }
        tmp[gbase[lo] + (i - lbase[lo])] = stage[i];
    }
}

// ---------------- pass 2: per-bucket node sort in LDS + CSR + dinv ----------------

__global__ __launch_bounds__(256) void k_bucket2(const int* __restrict__ bkbase,
                                                 const int2* __restrict__ tmp,
                                                 int2* __restrict__ sedge,
                                                 int* __restrict__ incl,
                                                 float* __restrict__ dinv) {
    __shared__ int2 stage[CAP2];
    __shared__ int2 sorted[CAP2];
    __shared__ int hist[BKN];
    __shared__ int sa[BKN], sb[BKN];
    __shared__ int lcur[BKN];
    int b = blockIdx.x;
    int t = threadIdx.x;
    int rbeg = bkbase[b], rend = bkbase[b + 1];
    int cnt = min(rend - rbeg, CAP2);     // CAP2 overflow statistically impossible; guard mem
    if (t < BKN) hist[t] = 0;
    __syncthreads();
    for (int i = t; i < cnt; i += 256) {
        int2 ed = tmp[rbeg + i];
        stage[i] = ed;
        atomicAdd(&hist[ed.x & (BKN - 1)], 1);
    }
    __syncthreads();
    if (t < BKN) sa[t] = hist[t];
    __syncthreads();
    int* src = sa; int* dst = sb;
#pragma unroll
    for (int off = 1; off < BKN; off <<= 1) {
        if (t < BKN) dst[t] = src[t] + ((t >= off) ? src[t - off] : 0);
        __syncthreads();
        int* tq = src; src = dst; dst = tq;
    }
    int node0 = b * BKN;
    int lincl = 0, lexcl = 0;
    if (t < BKN) {
        lincl = src[t];
        lexcl = lincl - hist[t];
        lcur[t] = lexcl;
        if (node0 + t < NN) incl[node0 + t] = rbeg + lincl;
    }
    __syncthreads();
    for (int i = t; i < cnt; i += 256) {
        int2 ed = stage[i];
        int pos = atomicAdd(&lcur[ed.x & (BKN - 1)], 1);
        sorted[pos] = ed;
    }
    __syncthreads();
    if (t < BKN && node0 + t < NN) {
        float s = 1.0f;      // self-loop
        for (int e = lexcl; e < lincl; ++e) s += __int_as_float(sorted[e].y);
        dinv[node0 + t] = rsqrtf(s);
    }
    for (int i = t; i < cnt; i += 256) {
        int2 ed = sorted[i];
        sedge[rbeg + i] = make_int2(ed.x >> BKS, ed.y);
    }
}

// norm = dinv[src] * w * dinv[dst], in-place; 16 lanes per node (coalesced)
__global__ __launch_bounds__(256) void k_snorm(const int* __restrict__ incl,
                                               int2* __restrict__ sedge,
                                               const float* __restrict__ dinv) {
    int node = blockIdx.x * 16 + (threadIdx.x >> 4);
    if (node >= NN) return;
    int fg = threadIdx.x & 15;
    int beg = (node == 0) ? 0 : incl[node - 1];
    int end = incl[node];
    float dc = dinv[node];
    for (int e = beg + fg; e < end; e += 16) {
        int2 ed = sedge[e];
        ed.y = __float_as_int(dinv[ed.x] * __int_as_float(ed.y) * dc);
        sedge[e] = ed;
    }
}

// ---------------- dense: Y[n,64] = X[n,64] @ W[64,64], 16 rows/block ----------------

__global__ __launch_bounds__(256) void k_mm64(const float* __restrict__ X,
                                              const float* __restrict__ W,
                                              float* __restrict__ Y) {
    __shared__ float sW[64 * 64];
    __shared__ float sX[16][64];
    int tid = threadIdx.x;
    int c  = tid & 63;
    int wv = tid >> 6;
    for (int i = tid; i < 64 * 64; i += 256) sW[i] = W[i];
    int r0 = blockIdx.x * 16;
#pragma unroll
    for (int i = tid; i < 16 * 64; i += 256)
        sX[i >> 6][i & 63] = X[(size_t)(r0 + (i >> 6)) * 64 + (i & 63)];
    __syncthreads();
    int rb = wv * 4;
    float a0 = 0.f, a1 = 0.f, a2 = 0.f, a3 = 0.f;
#pragma unroll
    for (int k = 0; k < 64; k += 4) {
        float4 x0 = *(const float4*)&sX[rb + 0][k];
        float4 x1 = *(const float4*)&sX[rb + 1][k];
        float4 x2 = *(const float4*)&sX[rb + 2][k];
        float4 x3 = *(const float4*)&sX[rb + 3][k];
        float wA = sW[(k + 0) * 64 + c];
        float wB = sW[(k + 1) * 64 + c];
        float wC = sW[(k + 2) * 64 + c];
        float wD = sW[(k + 3) * 64 + c];
        a0 += x0.x * wA + x0.y * wB + x0.z * wC + x0.w * wD;
        a1 += x1.x * wA + x1.y * wB + x1.z * wC + x1.w * wD;
        a2 += x2.x * wA + x2.y * wB + x2.z * wC + x2.w * wD;
        a3 += x3.x * wA + x3.y * wB + x3.z * wC + x3.w * wD;
    }
    Y[(size_t)(r0 + rb + 0) * 64 + c] = a0;
    Y[(size_t)(r0 + rb + 1) * 64 + c] = a1;
    Y[(size_t)(r0 + rb + 2) * 64 + c] = a2;
    Y[(size_t)(r0 + rb + 3) * 64 + c] = a3;
}

// ---------------- aggregation: one wave per node, float4 gather, 4 edges in flight ----

__global__ __launch_bounds__(256) void k_agg(const float* __restrict__ A,
                                             const int* __restrict__ incl,
                                             const int2* __restrict__ sedge,
                                             const float* __restrict__ dinv,
                                             const float* __restrict__ bias,
                                             float* __restrict__ B) {
    int node = blockIdx.x * 4 + (threadIdx.x >> 6);
    int lane = threadIdx.x & 63;
    int slot = lane >> 4;
    int fg   = lane & 15;
    int beg = (node == 0) ? 0 : incl[node - 1];
    int end = incl[node];
    int deg = end - beg;
    float ax = 0.f, ay = 0.f, az = 0.f, aw = 0.f;
    for (int base = 0; base < deg; base += 64) {
        int i = base + lane;
        int2 ed = (i < deg) ? sedge[beg + i] : make_int2(0, 0);
        int m = min(64, deg - base);
        int steps = (m + 3) >> 2;
        for (int t = 0; t < steps; ++t) {
            int idx = (t << 2) + slot;
            int   s  = __shfl(ed.x, idx);
            float nm = __int_as_float(__shfl(ed.y, idx));
            const float4 a = *(const float4*)(A + (size_t)s * 64 + (fg << 2));
            ax += a.x * nm; ay += a.y * nm; az += a.z * nm; aw += a.w * nm;
        }
    }
#pragma unroll
    for (int o = 16; o <= 32; o <<= 1) {
        ax += __shfl_xor(ax, o);
        ay += __shfl_xor(ay, o);
        az += __shfl_xor(az, o);
        aw += __shfl_xor(aw, o);
    }
    if (slot == 0) {
        float d = dinv[node];
        float d2 = d * d;
        const float4 self = *(const float4*)(A + (size_t)node * 64 + (fg << 2));
        const float4 bb   = *(const float4*)(bias + (fg << 2));
        float4 v;
        v.x = fmaxf(ax + self.x * d2 + bb.x, 0.f);
        v.y = fmaxf(ay + self.y * d2 + bb.y, 0.f);
        v.z = fmaxf(az + self.z * d2 + bb.z, 0.f);
        v.w = fmaxf(aw + self.w * d2 + bb.w, 0.f);
        *(float4*)(B + (size_t)node * 64 + (fg << 2)) = v;
    }
}

// ---------------- head: softmax(H @ Wout + bout) ----------------

__global__ __launch_bounds__(256) void k_out(const float* __restrict__ H,
                                             const float* __restrict__ Wout,
                                             const float* __restrict__ bout,
                                             float* __restrict__ out) {
    __shared__ float sW[64 * NCLS];
    __shared__ float sb[NCLS];
    for (int i = threadIdx.x; i < 64 * NCLS; i += 256) sW[i] = Wout[i];
    if (threadIdx.x < NCLS) sb[threadIdx.x] = bout[threadIdx.x];
    __syncthreads();
    int lr = threadIdx.x >> 4;
    int c  = threadIdx.x & 15;
    int r  = blockIdx.x * 16 + lr;
    const float* h = H + (size_t)r * 64;
    float acc = sb[c];
#pragma unroll
    for (int k = 0; k < 64; ++k)
        acc += h[k] * sW[k * NCLS + c];
    float m = acc;
#pragma unroll
    for (int o = 8; o >= 1; o >>= 1) m = fmaxf(m, __shfl_xor(m, o, 16));
    float ex = expf(acc - m);
    float s = ex;
#pragma unroll
    for (int o = 8; o >= 1; o >>= 1) s += __shfl_xor(s, o, 16);
    out[(size_t)r * NCLS + c] = ex / s;
}

// ---------------- launch ----------------

extern "C" void kernel_launch(void* const* d_in, const int* in_sizes, int n_in,
                              void* d_out, int out_size, void* d_ws, size_t ws_size,
                              hipStream_t stream) {
    const float* x    = (const float*)d_in[0];
    const int*   ei   = (const int*)d_in[1];
    const float* ew   = (const float*)d_in[2];
    const float* W1   = (const float*)d_in[3];
    const float* b1   = (const float*)d_in[4];
    const float* W2   = (const float*)d_in[5];
    const float* b2   = (const float*)d_in[6];
    const float* Wout = (const float*)d_in[7];
    const float* bout = (const float*)d_in[8];
    const int* row = ei;
    const int* col = ei + NE;

    // workspace (16B-aligned offsets); tmp aliases A (A written only after bucket2)
    int*   ip     = (int*)d_ws;
    int*   incl   = ip;                               // 50048
    float* dinv   = (float*)(ip + 50048);             // 50048
    int*   bkcnt  = ip + 100096;                      // 512
    int*   bkbase = ip + 100608;                      // 512
    int*   bkcur  = ip + 101120;                      // 512
    int2*  sedge  = (int2*)(ip + 101632);             // NE int2
    float* A      = (float*)(ip + 101632 + 2 * NE);   // NN*F
    int2*  tmp    = (int2*)A;                         // NE int2 (aliased, ok)
    float* B      = A + (size_t)NN * F;               // NN*F

    // sort pipeline
    k_zeroi<<<2, 256, 0, stream>>>(bkcnt, 512);
    k_bkhist<<<B1B, 256, 0, stream>>>(col, bkcnt);
    k_scan_bk<<<1, 512, 0, stream>>>(bkcnt, bkbase, bkcur);
    k_bucket1<<<B1B, 512, 0, stream>>>(row, col, ew, bkcur, tmp);
    k_bucket2<<<NBK, 256, 0, stream>>>(bkbase, tmp, sedge, incl, dinv);
    k_snorm<<<(NN + 15) / 16, 256, 0, stream>>>(incl, sedge, dinv);

    // layer 1
    k_mm64<<<NN / 16, 256, 0, stream>>>(x, W1, A);
    k_agg<<<NN / 4, 256, 0, stream>>>(A, incl, sedge, dinv, b1, B);

    // layer 2
    k_mm64<<<NN / 16, 256, 0, stream>>>(B, W2, A);
    k_agg<<<NN / 4, 256, 0, stream>>>(A, incl, sedge, dinv, b2, B);

    // head
    k_out<<<NN / 16, 256, 0, stream>>>(B, Wout, bout, (float*)d_out);
}

// Round 5
// 219.623 us; speedup vs baseline: 2.6189x; 1.0640x over previous
//
#include <hip/hip_runtime.h>
#include <math.h>

#define NN 50000
#define NE 800000
#define F 64
#define NCLS 16

#define BKS 7              // log2(nodes per bucket)
#define BKN 128            // nodes per bucket
#define NBK 391            // ceil(50000/128)
#define B1C 4096           // edges per bucket1 block
#define B1B 196            // ceil(NE/B1C)
#define CAP2 3072          // max edges per bucket

typedef unsigned short u16;
typedef __attribute__((ext_vector_type(8))) unsigned short ushort8v;

__device__ __forceinline__ float bf2f(u16 h) {
    return __uint_as_float((unsigned)h << 16);
}
__device__ __forceinline__ u16 f2bf(float f) {   // round-nearest-even
    unsigned u = __float_as_uint(f);
    return (u16)((u + 0x7fffu + ((u >> 16) & 1u)) >> 16);
}

__global__ void k_zeroi(int* __restrict__ p, int n) {
    int i = blockIdx.x * 256 + threadIdx.x;
    if (i < n) p[i] = 0;
}

// ---------------- pass 0: coarse bucket histogram ----------------

__global__ __launch_bounds__(256) void k_bkhist(const int* __restrict__ col,
                                                int* __restrict__ bkcnt) {
    __shared__ int h[NBK];
    for (int i = threadIdx.x; i < NBK; i += 256) h[i] = 0;
    __syncthreads();
    int stride = gridDim.x * 256;
    for (int e = blockIdx.x * 256 + threadIdx.x; e < NE; e += stride)
        atomicAdd(&h[col[e] >> BKS], 1);
    __syncthreads();
    for (int i = threadIdx.x; i < NBK; i += 256) {
        int v = h[i];
        if (v) atomicAdd(&bkcnt[i], v);
    }
}

// ---------------- scan bucket counts -> bases + cursors (1 block) ----------------

__global__ __launch_bounds__(512) void k_scan_bk(const int* __restrict__ bkcnt,
                                                 int* __restrict__ bkbase,
                                                 int* __restrict__ bkcur) {
    __shared__ int sa[512], sb[512];
    int t = threadIdx.x;
    int c = (t < NBK) ? bkcnt[t] : 0;
    sa[t] = c;
    __syncthreads();
    int* src = sa; int* dst = sb;
#pragma unroll
    for (int off = 1; off < 512; off <<= 1) {
        dst[t] = src[t] + ((t >= off) ? src[t - off] : 0);
        __syncthreads();
        int* tq = src; src = dst; dst = tq;
    }
    if (t < NBK) {
        int excl = src[t] - c;
        bkbase[t] = excl;
        bkcur[t]  = excl;
    }
    if (t == NBK) bkbase[t] = NE;
}

// ---------------- pass 1: group edges by bucket (LDS), flush contiguous runs ------

__global__ __launch_bounds__(512) void k_bucket1(const int* __restrict__ row,
                                                 const int* __restrict__ col,
                                                 const float* __restrict__ w,
                                                 int* __restrict__ bkcur,
                                                 int2* __restrict__ tmp) {
    __shared__ int hist[512];
    __shared__ int sa[512], sb[512];
    __shared__ int lbase[512];
    __shared__ int gbase[512];
    __shared__ int lcur[512];
    __shared__ int2 stage[B1C];
    int t = threadIdx.x;
    int e0 = blockIdx.x * B1C;
    int cnt = min(B1C, NE - e0);
    hist[t] = 0;
    __syncthreads();

    int mykey[8]; int myb[8]; int myw[8]; bool myv[8];
#pragma unroll
    for (int k = 0; k < 8; ++k) {
        int i = t + k * 512;
        myv[k] = (i < cnt);
        if (myv[k]) {
            int e = e0 + i;
            int c = col[e];
            myb[k]   = c >> BKS;
            mykey[k] = (row[e] << BKS) | (c & (BKN - 1));
            myw[k]   = __float_as_int(w[e]);
            atomicAdd(&hist[myb[k]], 1);
        }
    }
    __syncthreads();

    sa[t] = hist[t];
    __syncthreads();
    int* src = sa; int* dst = sb;
#pragma unroll
    for (int off = 1; off < 512; off <<= 1) {
        dst[t] = src[t] + ((t >= off) ? src[t - off] : 0);
        __syncthreads();
        int* tq = src; src = dst; dst = tq;
    }
    int lex = src[t] - hist[t];
    lbase[t] = lex;
    lcur[t]  = lex;
    gbase[t] = (t < NBK && hist[t] > 0) ? atomicAdd(&bkcur[t], hist[t]) : 0;
    __syncthreads();

#pragma unroll
    for (int k = 0; k < 8; ++k) {
        if (myv[k]) {
            int pos = atomicAdd(&lcur[myb[k]], 1);
            stage[pos] = make_int2(mykey[k], myw[k]);
        }
    }
    __syncthreads();

    for (int i = t; i < cnt; i += 512) {
        int lo = 0, hi = NBK;
        while (hi - lo > 1) {
            int mid = (lo + hi) >> 1;
            if (lbase[mid] <= i) lo = mid; else hi = mid;
        }
        tmp[gbase[lo] + (i - lbase[lo])] = stage[i];
    }
}

// ---------------- pass 2: per-bucket node sort in LDS + CSR + dinv ----------------

__global__ __launch_bounds__(256) void k_bucket2(const int* __restrict__ bkbase,
                                                 const int2* __restrict__ tmp,
                                                 int2* __restrict__ sedge,
                                                 int* __restrict__ incl,
                                                 float* __restrict__ dinv) {
    __shared__ int2 stage[CAP2];
    __shared__ int2 sorted[CAP2];
    __shared__ int hist[BKN];
    __shared__ int sa[BKN], sb[BKN];
    __shared__ int lcur[BKN];
    int b = blockIdx.x;
    int t = threadIdx.x;
    int rbeg = bkbase[b], rend = bkbase[b + 1];
    int cnt = min(rend - rbeg, CAP2);
    if (t < BKN) hist[t] = 0;
    __syncthreads();
    for (int i = t; i < cnt; i += 256) {
        int2 ed = tmp[rbeg + i];
        stage[i] = ed;
        atomicAdd(&hist[ed.x & (BKN - 1)], 1);
    }
    __syncthreads();
    if (t < BKN) sa[t] = hist[t];
    __syncthreads();
    int* src = sa; int* dst = sb;
#pragma unroll
    for (int off = 1; off < BKN; off <<= 1) {
        if (t < BKN) dst[t] = src[t] + ((t >= off) ? src[t - off] : 0);
        __syncthreads();
        int* tq = src; src = dst; dst = tq;
    }
    int node0 = b * BKN;
    int lincl = 0, lexcl = 0;
    if (t < BKN) {
        lincl = src[t];
        lexcl = lincl - hist[t];
        lcur[t] = lexcl;
        if (node0 + t < NN) incl[node0 + t] = rbeg + lincl;
    }
    __syncthreads();
    for (int i = t; i < cnt; i += 256) {
        int2 ed = stage[i];
        int pos = atomicAdd(&lcur[ed.x & (BKN - 1)], 1);
        sorted[pos] = ed;
    }
    __syncthreads();
    if (t < BKN && node0 + t < NN) {
        float s = 1.0f;
        for (int e = lexcl; e < lincl; ++e) s += __int_as_float(sorted[e].y);
        dinv[node0 + t] = rsqrtf(s);
    }
    for (int i = t; i < cnt; i += 256) {
        int2 ed = sorted[i];
        sedge[rbeg + i] = make_int2(ed.x >> BKS, ed.y);   // {src, raw weight}
    }
}

// ---------------- dense: Y[n,64] = X[n,64] @ W[64,64] -> bf16 ----------------

template<bool BF>
__global__ __launch_bounds__(256) void k_mm64(const void* __restrict__ Xv,
                                              const float* __restrict__ W,
                                              u16* __restrict__ Y) {
    __shared__ float sW[64 * 64];
    __shared__ float sX[16][64];
    int tid = threadIdx.x;
    int c  = tid & 63;
    int wv = tid >> 6;
    for (int i = tid; i < 64 * 64; i += 256) sW[i] = W[i];
    int r0 = blockIdx.x * 16;
#pragma unroll
    for (int i = tid; i < 16 * 64; i += 256) {
        size_t idx = (size_t)(r0 + (i >> 6)) * 64 + (i & 63);
        if (BF) sX[i >> 6][i & 63] = bf2f(((const u16*)Xv)[idx]);
        else    sX[i >> 6][i & 63] = ((const float*)Xv)[idx];
    }
    __syncthreads();
    int rb = wv * 4;
    float a0 = 0.f, a1 = 0.f, a2 = 0.f, a3 = 0.f;
#pragma unroll
    for (int k = 0; k < 64; k += 4) {
        float4 x0 = *(const float4*)&sX[rb + 0][k];
        float4 x1 = *(const float4*)&sX[rb + 1][k];
        float4 x2 = *(const float4*)&sX[rb + 2][k];
        float4 x3 = *(const float4*)&sX[rb + 3][k];
        float wA = sW[(k + 0) * 64 + c];
        float wB = sW[(k + 1) * 64 + c];
        float wC = sW[(k + 2) * 64 + c];
        float wD = sW[(k + 3) * 64 + c];
        a0 += x0.x * wA + x0.y * wB + x0.z * wC + x0.w * wD;
        a1 += x1.x * wA + x1.y * wB + x1.z * wC + x1.w * wD;
        a2 += x2.x * wA + x2.y * wB + x2.z * wC + x2.w * wD;
        a3 += x3.x * wA + x3.y * wB + x3.z * wC + x3.w * wD;
    }
    Y[(size_t)(r0 + rb + 0) * 64 + c] = f2bf(a0);
    Y[(size_t)(r0 + rb + 1) * 64 + c] = f2bf(a1);
    Y[(size_t)(r0 + rb + 2) * 64 + c] = f2bf(a2);
    Y[(size_t)(r0 + rb + 3) * 64 + c] = f2bf(a3);
}

// ---------------- aggregation: one wave/node, bf16 gather, 8 edges in flight ----
// norm computed on the fly: norm = (w * dinv[src]) * dinv[dst]
// HEAD: fuse logits @ Wout + bout + softmax -> out

template<bool HEAD>
__global__ __launch_bounds__(256) void k_agg(const u16* __restrict__ A,
                                             const int* __restrict__ incl,
                                             const int2* __restrict__ sedge,
                                             const float* __restrict__ dinv,
                                             const float* __restrict__ bias,
                                             u16* __restrict__ B,
                                             const float* __restrict__ Wout,
                                             const float* __restrict__ bout,
                                             float* __restrict__ out) {
    __shared__ float sWout[64 * NCLS];
    __shared__ float sh[4][64];
    int tid  = threadIdx.x;
    int wv   = tid >> 6;
    int node = blockIdx.x * 4 + wv;       // 12500*4 = 50000 exact
    int lane = tid & 63;
    int slot = lane >> 3;                 // 0..7 edge slot
    int fg   = lane & 7;                  // features fg*8 .. fg*8+7
    if (HEAD) {
        for (int i = tid; i < 64 * NCLS; i += 256) sWout[i] = Wout[i];
    }
    int beg = (node == 0) ? 0 : incl[node - 1];
    int end = incl[node];
    int deg = end - beg;
    float acc[8] = {0.f, 0.f, 0.f, 0.f, 0.f, 0.f, 0.f, 0.f};
    for (int base = 0; base < deg; base += 64) {
        int i = base + lane;
        int2 ed = (i < deg) ? sedge[beg + i] : make_int2(0, 0);  // w=0 pad
        float nmr = __int_as_float(ed.y) * dinv[ed.x];           // w * dinv[src]
        int m = min(64, deg - base);
        int steps = (m + 7) >> 3;
        for (int t = 0; t < steps; ++t) {
            int idx = (t << 3) + slot;
            int   s  = __shfl(ed.x, idx);
            float nm = __shfl(nmr, idx);
            const ushort8v a = *(const ushort8v*)(A + (size_t)s * 64 + (fg << 3));
#pragma unroll
            for (int j = 0; j < 8; ++j) acc[j] += bf2f(a[j]) * nm;
        }
    }
    // reduce across 8 slots
#pragma unroll
    for (int o = 8; o <= 32; o <<= 1) {
#pragma unroll
        for (int j = 0; j < 8; ++j) acc[j] += __shfl_xor(acc[j], o);
    }
    float dc = dinv[node];
    if (slot == 0) {
        float d2 = dc * dc;
        const ushort8v self = *(const ushort8v*)(A + (size_t)node * 64 + (fg << 3));
        const float4 bb0 = *(const float4*)(bias + (fg << 3));
        const float4 bb1 = *(const float4*)(bias + (fg << 3) + 4);
        float bbv[8] = {bb0.x, bb0.y, bb0.z, bb0.w, bb1.x, bb1.y, bb1.z, bb1.w};
        ushort8v ov;
#pragma unroll
        for (int j = 0; j < 8; ++j) {
            float v = fmaxf(acc[j] * dc + bf2f(self[j]) * d2 + bbv[j], 0.f);
            ov[j] = f2bf(v);
            if (HEAD) sh[wv][(fg << 3) + j] = v;
        }
        *(ushort8v*)(B + (size_t)node * 64 + (fg << 3)) = ov;
    }
    if (HEAD) {
        __syncthreads();
        int c = lane & 15, q = lane >> 4;
        float p = 0.f;
#pragma unroll
        for (int k = 0; k < 16; ++k)
            p += sh[wv][q * 16 + k] * sWout[(q * 16 + k) * NCLS + c];
        p += __shfl_xor(p, 16);
        p += __shfl_xor(p, 32);
        p += bout[c];
        float mx = p;
#pragma unroll
        for (int o = 8; o >= 1; o >>= 1) mx = fmaxf(mx, __shfl_xor(mx, o, 16));
        float ex = expf(p - mx);
        float s = ex;
#pragma unroll
        for (int o = 8; o >= 1; o >>= 1) s += __shfl_xor(s, o, 16);
        if (lane < 16) out[(size_t)node * NCLS + c] = ex / s;
    }
}

// ---------------- launch ----------------

extern "C" void kernel_launch(void* const* d_in, const int* in_sizes, int n_in,
                              void* d_out, int out_size, void* d_ws, size_t ws_size,
                              hipStream_t stream) {
    const float* x    = (const float*)d_in[0];
    const int*   ei   = (const int*)d_in[1];
    const float* ew   = (const float*)d_in[2];
    const float* W1   = (const float*)d_in[3];
    const float* b1   = (const float*)d_in[4];
    const float* W2   = (const float*)d_in[5];
    const float* b2   = (const float*)d_in[6];
    const float* Wout = (const float*)d_in[7];
    const float* bout = (const float*)d_in[8];
    const int* row = ei;
    const int* col = ei + NE;

    // workspace; tmp aliases A+B region (A/B written only after bucket2 consumed tmp)
    int*   ip     = (int*)d_ws;
    int*   incl   = ip;                               // 50048
    float* dinv   = (float*)(ip + 50048);             // 50048
    int*   bkcnt  = ip + 100096;                      // 512
    int*   bkbase = ip + 100608;                      // 512
    int*   bkcur  = ip + 101120;                      // 512
    int2*  sedge  = (int2*)(ip + 101632);             // NE int2
    u16*   A      = (u16*)(ip + 101632 + 2 * NE);     // NN*64 bf16 (3.2M u16 = 1.6M int)
    u16*   B      = (u16*)(ip + 101632 + 2 * NE + 1600000);
    int2*  tmp    = (int2*)A;                         // NE int2 aliased over A+B

    // sort pipeline
    k_zeroi<<<2, 256, 0, stream>>>(bkcnt, 512);
    k_bkhist<<<B1B, 256, 0, stream>>>(col, bkcnt);
    k_scan_bk<<<1, 512, 0, stream>>>(bkcnt, bkbase, bkcur);
    k_bucket1<<<B1B, 512, 0, stream>>>(row, col, ew, bkcur, tmp);
    k_bucket2<<<NBK, 256, 0, stream>>>(bkbase, tmp, sedge, incl, dinv);

    // layer 1
    k_mm64<false><<<NN / 16, 256, 0, stream>>>(x, W1, A);
    k_agg<false><<<NN / 4, 256, 0, stream>>>(A, incl, sedge, dinv, b1, B,
                                             nullptr, nullptr, nullptr);
    // layer 2 + fused head
    k_mm64<true><<<NN / 16, 256, 0, stream>>>(B, W2, A);
    k_agg<true><<<NN / 4, 256, 0, stream>>>(A, incl, sedge, dinv, b2, B,
                                            Wout, bout, (float*)d_out);
}